// Round 1
// baseline (197.203 us; speedup 1.0000x reference)
//
#include <hip/hip_runtime.h>
#include <math.h>

#define XROW 516      // 8-neighbor row stride (4*128 + 4 pad) -> h-stride mod 32 == 4
#define SELFROW 132
#define WTROW 132
#define WOROW 130

__global__ __launch_bounds__(256) void ln_kernel(
    const float* __restrict__ s_feats,
    const float* __restrict__ ln_w,
    const float* __restrict__ ln_b,
    float* __restrict__ x, int N)
{
    int wv = threadIdx.x >> 6;
    int lane = threadIdx.x & 63;
    int n = blockIdx.x * 4 + wv;
    if (n >= N) return;
    const float* s = s_feats + (size_t)n * 512;
    float s0a = s[lane], s0b = s[lane + 64];
    float m = s0a + s0b;
    #pragma unroll
    for (int off = 1; off <= 32; off <<= 1) m += __shfl_xor(m, off);
    m *= (1.0f / 128.0f);
    float x0a = s0a - m, x0b = s0b - m;
    float sq0 = x0a * x0a + x0b * x0b;
    float va[3], vb[3];
    float sq1 = 0.0f;
    #pragma unroll
    for (int mm = 0; mm < 3; mm++) {
        va[mm] = s[(mm + 1) * 128 + lane];
        vb[mm] = s[(mm + 1) * 128 + lane + 64];
        sq1 += va[mm] * va[mm] + vb[mm] * vb[mm];
    }
    #pragma unroll
    for (int off = 1; off <= 32; off <<= 1) {
        sq0 += __shfl_xor(sq0, off);
        sq1 += __shfl_xor(sq1, off);
    }
    float r0 = rsqrtf(sq0 * (1.0f / 128.0f) + 1e-5f);
    float r1 = rsqrtf(sq1 * (1.0f / 128.0f) + 1e-5f);
    float* xo = x + (size_t)n * 512;
    xo[lane]      = x0a * r0 * ln_w[lane]      + ln_b[lane];
    xo[lane + 64] = x0b * r0 * ln_w[lane + 64] + ln_b[lane + 64];
    #pragma unroll
    for (int mm = 0; mm < 3; mm++) {
        xo[(mm + 1) * 128 + lane]      = va[mm] * r1 * ln_w[128 + lane];
        xo[(mm + 1) * 128 + lane + 64] = vb[mm] * r1 * ln_w[128 + lane + 64];
    }
}

__global__ __launch_bounds__(128) void main_kernel(
    const float* __restrict__ x,          // (N,4,128) post-LN
    const float* __restrict__ s_points,   // (N,3)
    const int*   __restrict__ nbr,        // (N,9)
    const float* __restrict__ w_in,       // (256,8)
    const float* __restrict__ w0,         // (16,16)
    const float* __restrict__ wr,         // (8,8)
    const float* __restrict__ wi,         // (8,8)
    const float* __restrict__ w_out,      // (8,128)
    float* __restrict__ out, int N)
{
    __shared__ float x_lds[2][8 * XROW];
    __shared__ float xself[2][4 * SELFROW];
    __shared__ float wt[8 * WTROW];        // w_in[0:128,:] transposed [k][c]
    __shared__ float wt2[8 * WTROW];       // w_in[128:256,:] transposed [k][c]
    __shared__ float w0s[256];
    __shared__ float wrs[64], wis[64];
    __shared__ float wos[8 * WOROW];       // w_out [k][c]
    __shared__ float Ssh[2][32];
    __shared__ float accsh[2][32];

    int tid = threadIdx.x;
    // ---- block-cooperative weight staging ----
    for (int i = tid; i < 2048; i += 128) {
        int c = i >> 3, k = i & 7;
        float v = w_in[i];
        if (c < 128) wt[k * WTROW + c] = v;
        else         wt2[k * WTROW + (c - 128)] = v;
    }
    for (int i = tid; i < 256; i += 128) w0s[i] = w0[i];
    if (tid < 64) { wrs[tid] = wr[tid]; wis[tid] = wi[tid]; }
    for (int i = tid; i < 1024; i += 128) {
        int k = i >> 7, c = i & 127;
        wos[k * WOROW + c] = w_out[i];
    }

    int wv = tid >> 6, lane = tid & 63;
    int n = blockIdx.x * 2 + wv;
    bool valid = n < N;
    int h = lane >> 3, k = lane & 7;

    float D1[3][3];
    int idxh = 0;
    if (valid) {
        idxh = nbr[n * 9 + 1 + h];
        bool maskh = idxh < N;
        float px = s_points[n * 3], py = s_points[n * 3 + 1], pz = s_points[n * 3 + 2];
        float nx = maskh ? s_points[idxh * 3]     : 0.0f;
        float ny = maskh ? s_points[idxh * 3 + 1] : 0.0f;
        float nz = maskh ? s_points[idxh * 3 + 2] : 0.0f;
        float vx = nx - px, vy = ny - py, vz = nz - pz;
        float nn = sqrtf(vx * vx + vy * vy + vz * vz);
        float inv = 1.0f / (nn + 1e-9f);
        float ux = vx * inv, uy = vy * inv, uz = vz * inv;
        float cz = uz;
        float kx = uy, ky = -ux;
        bool safe = cz > -0.999f;
        float id = safe ? 1.0f / (1.0f + cz) : 1.0f;
        float R00, R01, R02, R10, R11, R12, R20, R21, R22;
        if (safe) {
            R00 = 1.0f - ky * ky * id; R01 = kx * ky * id;        R02 = ky;
            R10 = kx * ky * id;        R11 = 1.0f - kx * kx * id; R12 = -kx;
            R20 = -ky;                 R21 = kx;                  R22 = 1.0f - (kx * kx + ky * ky) * id;
        } else {
            R00 = 1.0f; R01 = 0.0f; R02 = 0.0f;
            R10 = 0.0f; R11 = -1.0f; R12 = 0.0f;
            R20 = 0.0f; R21 = 0.0f; R22 = -1.0f;
        }
        // D1[i][l] = R[p[i]][p[l]], p = {1,2,0}
        D1[0][0] = R11; D1[0][1] = R12; D1[0][2] = R10;
        D1[1][0] = R21; D1[1][1] = R22; D1[1][2] = R20;
        D1[2][0] = R01; D1[2][1] = R02; D1[2][2] = R00;

        // ---- stage 8 neighbor rows (masked) ----
        for (int r = 0; r < 8; r++) {
            int ir = __shfl(idxh, r * 8);
            bool mr = ir < N;
            const float4* src = (const float4*)(x + (size_t)ir * 512);
            float4 a = mr ? src[lane]      : float4{0.f, 0.f, 0.f, 0.f};
            float4 b = mr ? src[lane + 64] : float4{0.f, 0.f, 0.f, 0.f};
            *(float4*)&x_lds[wv][r * XROW + lane * 4]       = a;
            *(float4*)&x_lds[wv][r * XROW + 256 + lane * 4] = b;
        }
        // ---- stage self row into padded [m][c] layout ----
        const float4* ssrc = (const float4*)(x + (size_t)n * 512);
        float4 a = ssrc[lane];
        float4 b = ssrc[lane + 64];
        int e = lane * 4;
        *(float4*)&xself[wv][(e >> 7) * SELFROW + (e & 127)] = a;
        e = 256 + lane * 4;
        *(float4*)&xself[wv][(e >> 7) * SELFROW + (e & 127)] = b;
    }
    __syncthreads();

    // ---- self contribution: S[m][k] = sum_c x_self[m][c] * w_in[128+c][k] ----
    if (valid && lane < 32) {
        int sm = lane >> 3, sk = lane & 7;
        float S = 0.0f;
        const float* xs = &xself[wv][sm * SELFROW];
        const float* w2 = &wt2[sk * WTROW];
        #pragma unroll 4
        for (int c4 = 0; c4 < 32; c4++) {
            float4 a = *(const float4*)&xs[c4 * 4];
            float4 b = *(const float4*)&w2[c4 * 4];
            S += a.x * b.x + a.y * b.y + a.z * b.z + a.w * b.w;
        }
        Ssh[wv][sm * 8 + sk] = S;
    }
    __syncthreads();

    float f[4];
    if (valid) {
        // ---- main contraction: msg[m] = sum_c nfts[h][m][c] * w_in[c][k] ----
        float msg[4] = {0.f, 0.f, 0.f, 0.f};
        const float* xb = &x_lds[wv][h * XROW];
        const float* wb = &wt[k * WTROW];
        #pragma unroll 4
        for (int c4 = 0; c4 < 32; c4++) {
            float4 wvv = *(const float4*)&wb[c4 * 4];
            #pragma unroll
            for (int mq = 0; mq < 4; mq++) {
                float4 xv = *(const float4*)&xb[mq * 128 + c4 * 4];
                msg[mq] += xv.x * wvv.x + xv.y * wvv.y + xv.z * wvv.z + xv.w * wvv.w;
            }
        }
        #pragma unroll
        for (int mq = 0; mq < 4; mq++) msg[mq] += Ssh[wv][mq * 8 + k];

        // ---- l1 = D1 @ msg[1:4] ----
        float l1[3];
        #pragma unroll
        for (int i = 0; i < 3; i++)
            l1[i] = D1[i][0] * msg[1] + D1[i][1] * msg[2] + D1[i][2] * msg[3];

        // ---- m0 = [msg0, l1_1] @ so2_w0 ----
        int base = lane & 56;
        float m00 = 0.f, m01 = 0.f;
        #pragma unroll
        for (int j = 0; j < 8; j++) {
            float v0 = __shfl(msg[0], base + j);
            float v1 = __shfl(l1[1], base + j);
            m00 += v0 * w0s[j * 16 + k]     + v1 * w0s[(8 + j) * 16 + k];
            m01 += v0 * w0s[j * 16 + 8 + k] + v1 * w0s[(8 + j) * 16 + 8 + k];
        }
        // ---- SO(2) rotation on (l1_0, l1_2) ----
        float yp = 0.f, ym = 0.f;
        #pragma unroll
        for (int j = 0; j < 8; j++) {
            float vm = __shfl(l1[0], base + j);
            float vp = __shfl(l1[2], base + j);
            float r  = wrs[j * 8 + k];
            float ii = wis[j * 8 + k];
            yp += vp * r - vm * ii;
            ym += vm * r + vp * ii;
        }
        // ---- out_l1 = D1^T @ [ym, m01, yp] ----
        float pre0 = ym, pre1 = m01, pre2 = yp;
        f[0] = m00;
        #pragma unroll
        for (int i = 0; i < 3; i++)
            f[1 + i] = D1[0][i] * pre0 + D1[1][i] * pre1 + D1[2][i] * pre2;

        // ---- reduce over neighbors (h groups) ----
        #pragma unroll
        for (int mq = 0; mq < 4; mq++) {
            f[mq] += __shfl_xor(f[mq], 8);
            f[mq] += __shfl_xor(f[mq], 16);
            f[mq] += __shfl_xor(f[mq], 32);
        }
        if (h == 0) {
            #pragma unroll
            for (int mq = 0; mq < 4; mq++) accsh[wv][mq * 8 + k] = f[mq];
        }
    }
    __syncthreads();

    if (valid) {
        // ---- out[n][m][c] = sum_k acc[m][k] * w_out[k][c], lane -> c0=2*lane ----
        float o0[4] = {0.f, 0.f, 0.f, 0.f}, o1[4] = {0.f, 0.f, 0.f, 0.f};
        #pragma unroll
        for (int kk = 0; kk < 8; kk++) {
            float2 wv2 = *(const float2*)&wos[kk * WOROW + lane * 2];
            #pragma unroll
            for (int mq = 0; mq < 4; mq++) {
                float am = accsh[wv][mq * 8 + kk];
                o0[mq] += am * wv2.x;
                o1[mq] += am * wv2.y;
            }
        }
        float* op = out + (size_t)n * 512;
        #pragma unroll
        for (int mq = 0; mq < 4; mq++) {
            float2 o = {o0[mq], o1[mq]};
            *(float2*)&op[mq * 128 + lane * 2] = o;
        }
    }
}

extern "C" void kernel_launch(void* const* d_in, const int* in_sizes, int n_in,
                              void* d_out, int out_size, void* d_ws, size_t ws_size,
                              hipStream_t stream) {
    const float* s_feats = (const float*)d_in[0];
    const float* s_points = (const float*)d_in[1];
    const int* nbr = (const int*)d_in[2];
    const float* ln_w = (const float*)d_in[3];
    const float* ln_b = (const float*)d_in[4];
    const float* w_in = (const float*)d_in[5];
    const float* w_out = (const float*)d_in[6];
    const float* so2_w0 = (const float*)d_in[7];
    const float* so2_wr = (const float*)d_in[8];
    const float* so2_wi = (const float*)d_in[9];
    float* out = (float*)d_out;
    float* x = (float*)d_ws;   // (N,4,128) post-LN features

    int N = in_sizes[0] / 512;

    ln_kernel<<<(N + 3) / 4, 256, 0, stream>>>(s_feats, ln_w, ln_b, x, N);
    main_kernel<<<(N + 1) / 2, 128, 0, stream>>>(x, s_points, nbr, w_in, so2_w0,
                                                 so2_wr, so2_wi, w_out, out, N);
}

// Round 2
// 99.514 us; speedup vs baseline: 1.9817x; 1.9817x over previous
//
#include <hip/hip_runtime.h>
#include <math.h>

// ---- cross-lane helpers (LDS-pipe ds_swizzle, single instruction) ----
#define SWZ8(x)  __int_as_float(__builtin_amdgcn_ds_swizzle(__float_as_int(x), 0x201F)) // lane^8
#define SWZ16(x) __int_as_float(__builtin_amdgcn_ds_swizzle(__float_as_int(x), 0x401F)) // lane^16
#define SX32(x)  __shfl_xor((x), 32)
// broadcast from lane (group8-base | J) within each 32-half
#define BC(x, J) __int_as_float(__builtin_amdgcn_ds_swizzle(__float_as_int(x), (((J) << 5) | 0x18)))

// ============================================================================
// K1: fused LayerNorm + input projections.
//   y[n][m][k] = LN(s_feats[n])[m] . w_in[0:128, k]     (neighbor-side proj)
//   S[n][m][k] = LN(s_feats[n])[m] . w_in[128:256, k]   (self-side proj)
// stored as ys[n][64]: [k*4+m] = y, [32 + k*4+m] = S
// lane = (cg = lane>>3 owns 16 channels, kq = lane&7 owns output k)
// ============================================================================
__global__ __launch_bounds__(256, 4) void k1_ln_proj(
    const float* __restrict__ s_feats,
    const float* __restrict__ ln_w,   // (2,128)
    const float* __restrict__ ln_b,   // (128)
    const float* __restrict__ w_in,   // (256,8)
    float* __restrict__ ys,           // (N,64)
    int N, int nwaves)
{
    const int lane = threadIdx.x & 63;
    const int kq = lane & 7;
    const int cg = lane >> 3;
    const int wave = blockIdx.x * (blockDim.x >> 6) + (threadIdx.x >> 6);

    // per-lane constant weights: w_in premultiplied by ln scale rows
    float wa0[16], wa1[16], wb0[16], wb1[16];
    float B1 = 0.f, C1 = 0.f, B2 = 0.f, C2 = 0.f;
    #pragma unroll
    for (int t = 0; t < 16; t++) {
        int c = cg * 16 + t;
        float w1 = w_in[c * 8 + kq];
        float w2 = w_in[(128 + c) * 8 + kq];
        float l0 = ln_w[c], l1 = ln_w[128 + c], lb = ln_b[c];
        wa0[t] = w1 * l0; wa1[t] = w1 * l1;
        wb0[t] = w2 * l0; wb1[t] = w2 * l1;
        B1 += w1 * l0; C1 += lb * w1;
        B2 += w2 * l0; C2 += lb * w2;
    }
    // reduce B/C across the 8 cg groups (once per kernel)
    B1 += SWZ8(B1);  C1 += SWZ8(C1);  B2 += SWZ8(B2);  C2 += SWZ8(C2);
    B1 += SWZ16(B1); C1 += SWZ16(C1); B2 += SWZ16(B2); C2 += SWZ16(C2);
    B1 += SX32(B1);  C1 += SX32(C1);  B2 += SX32(B2);  C2 += SX32(C2);

    for (int n = wave; n < N; n += nwaves) {
        const float* sp = s_feats + (size_t)n * 512 + cg * 16;
        float accY[4] = {0.f, 0.f, 0.f, 0.f};
        float accS[4] = {0.f, 0.f, 0.f, 0.f};
        float ssum = 0.f, sq0 = 0.f, sq1 = 0.f;
        #pragma unroll
        for (int m = 0; m < 4; m++) {
            #pragma unroll
            for (int i = 0; i < 4; i++) {
                float4 v = *(const float4*)(sp + m * 128 + i * 4);
                float e0 = v.x, e1 = v.y, e2 = v.z, e3 = v.w;
                if (m == 0) {
                    accY[0] += e0 * wa0[i*4+0] + e1 * wa0[i*4+1] + e2 * wa0[i*4+2] + e3 * wa0[i*4+3];
                    accS[0] += e0 * wb0[i*4+0] + e1 * wb0[i*4+1] + e2 * wb0[i*4+2] + e3 * wb0[i*4+3];
                    ssum += e0 + e1 + e2 + e3;
                    sq0  += e0 * e0 + e1 * e1 + e2 * e2 + e3 * e3;
                } else {
                    accY[m] += e0 * wa1[i*4+0] + e1 * wa1[i*4+1] + e2 * wa1[i*4+2] + e3 * wa1[i*4+3];
                    accS[m] += e0 * wb1[i*4+0] + e1 * wb1[i*4+1] + e2 * wb1[i*4+2] + e3 * wb1[i*4+3];
                    sq1  += e0 * e0 + e1 * e1 + e2 * e2 + e3 * e3;
                }
            }
        }
        // reduce 11 partials over cg (kq preserved)
        #define RED_ALL(FN) \
            accY[0] += FN(accY[0]); accY[1] += FN(accY[1]); accY[2] += FN(accY[2]); accY[3] += FN(accY[3]); \
            accS[0] += FN(accS[0]); accS[1] += FN(accS[1]); accS[2] += FN(accS[2]); accS[3] += FN(accS[3]); \
            ssum += FN(ssum); sq0 += FN(sq0); sq1 += FN(sq1);
        RED_ALL(SWZ8)
        RED_ALL(SWZ16)
        RED_ALL(SX32)
        #undef RED_ALL

        float mean = ssum * (1.0f / 128.0f);
        float r0 = rsqrtf((sq0 - ssum * mean) * (1.0f / 128.0f) + 1e-5f);
        float r1 = rsqrtf(sq1 * (1.0f / 128.0f) + 1e-5f);

        // lane cg selects which of the 8 per-kq outputs it stores (no array indexing)
        float aA = (cg & 2) ? ((cg & 1) ? accY[3] : accY[2]) : ((cg & 1) ? accY[1] : accY[0]);
        float aB = (cg & 2) ? ((cg & 1) ? accS[3] : accS[2]) : ((cg & 1) ? accS[1] : accS[0]);
        float av = (cg & 4) ? aB : aA;
        float Bv = (cg & 4) ? B2 : B1;
        float Cv = (cg & 4) ? C2 : C1;
        bool isM0 = (cg & 3) == 0;
        float outv = isM0 ? (r0 * (av - mean * Bv) + Cv) : (r1 * av);
        ys[(size_t)n * 64 + kq * 4 + (cg & 3) + ((cg & 4) << 3)] = outv;
    }
}

// ============================================================================
// K2: per-edge tensor product. lane = (h = lane>>3, k = lane&7), 1 node/wave.
//   msg[m][k] = y[idx_h][m][k]*mask + S[n][m][k]; rotate/mix; sum over h.
// writes acc[n][32] ([k*4+m])
// ============================================================================
__global__ __launch_bounds__(256, 4) void k2_edges(
    const float* __restrict__ ys,       // (N,64)
    const float* __restrict__ s_points, // (N,3)
    const int*   __restrict__ nbr,      // (N,9)
    const float* __restrict__ w0,       // (16,16)
    const float* __restrict__ wr,       // (8,8)
    const float* __restrict__ wi,       // (8,8)
    float* __restrict__ acc,            // (N,32)
    int N, int nwaves)
{
    const int lane = threadIdx.x & 63;
    const int h = lane >> 3, k = lane & 7;
    const int wave = blockIdx.x * (blockDim.x >> 6) + (threadIdx.x >> 6);

    // per-lane constant mixing weights
    float c00[8], c08[8], c10[8], c18[8], cwr[8], cwi[8];
    #pragma unroll
    for (int j = 0; j < 8; j++) {
        c00[j] = w0[j * 16 + k];
        c08[j] = w0[(8 + j) * 16 + k];
        c10[j] = w0[j * 16 + 8 + k];
        c18[j] = w0[(8 + j) * 16 + 8 + k];
        cwr[j] = wr[j * 8 + k];
        cwi[j] = wi[j * 8 + k];
    }

    for (int n = wave; n < N; n += nwaves) {
        int idx = nbr[n * 9 + 1 + h];
        bool mk = idx < N;
        float px = s_points[n * 3], py = s_points[n * 3 + 1], pz = s_points[n * 3 + 2];
        float nx = mk ? s_points[idx * 3]     : 0.f;
        float ny = mk ? s_points[idx * 3 + 1] : 0.f;
        float nz = mk ? s_points[idx * 3 + 2] : 0.f;
        float vx = nx - px, vy = ny - py, vz = nz - pz;
        float nn = sqrtf(vx * vx + vy * vy + vz * vz);
        float inv = 1.0f / (nn + 1e-9f);
        float ux = vx * inv, uy = vy * inv, uz = vz * inv;
        float cz = uz;
        float kx = uy, ky = -ux;
        bool safe = cz > -0.999f;
        float id = safe ? 1.0f / (1.0f + cz) : 1.0f;
        float D1[3][3];
        {
            float R00, R01, R02, R10, R11, R12, R20, R21, R22;
            if (safe) {
                R00 = 1.0f - ky * ky * id; R01 = kx * ky * id;        R02 = ky;
                R10 = kx * ky * id;        R11 = 1.0f - kx * kx * id; R12 = -kx;
                R20 = -ky;                 R21 = kx;                  R22 = 1.0f - (kx * kx + ky * ky) * id;
            } else {
                R00 = 1.0f; R01 = 0.0f; R02 = 0.0f;
                R10 = 0.0f; R11 = -1.0f; R12 = 0.0f;
                R20 = 0.0f; R21 = 0.0f; R22 = -1.0f;
            }
            D1[0][0] = R11; D1[0][1] = R12; D1[0][2] = R10;
            D1[1][0] = R21; D1[1][1] = R22; D1[1][2] = R20;
            D1[2][0] = R01; D1[2][1] = R02; D1[2][2] = R00;
        }

        float4 yv = mk ? *(const float4*)(ys + (size_t)idx * 64 + k * 4)
                       : float4{0.f, 0.f, 0.f, 0.f};
        float4 sv = *(const float4*)(ys + (size_t)n * 64 + 32 + k * 4);
        float msg0 = yv.x + sv.x;
        float msg1 = yv.y + sv.y;
        float msg2 = yv.z + sv.z;
        float msg3 = yv.w + sv.w;

        float l1_0 = D1[0][0] * msg1 + D1[0][1] * msg2 + D1[0][2] * msg3;
        float l1_1 = D1[1][0] * msg1 + D1[1][1] * msg2 + D1[1][2] * msg3;
        float l1_2 = D1[2][0] * msg1 + D1[2][1] * msg2 + D1[2][2] * msg3;

        float m00 = 0.f, m01 = 0.f, ypl = 0.f, yml = 0.f;
        #define STEP(J) { \
            float v0 = BC(msg0, J), v1 = BC(l1_1, J), vm = BC(l1_0, J), vp = BC(l1_2, J); \
            m00 += v0 * c00[J] + v1 * c08[J]; \
            m01 += v0 * c10[J] + v1 * c18[J]; \
            ypl += vp * cwr[J] - vm * cwi[J]; \
            yml += vm * cwr[J] + vp * cwi[J]; }
        STEP(0) STEP(1) STEP(2) STEP(3) STEP(4) STEP(5) STEP(6) STEP(7)
        #undef STEP

        float f0 = m00;
        float f1 = D1[0][0] * yml + D1[1][0] * m01 + D1[2][0] * ypl;
        float f2 = D1[0][1] * yml + D1[1][1] * m01 + D1[2][1] * ypl;
        float f3 = D1[0][2] * yml + D1[1][2] * m01 + D1[2][2] * ypl;

        // reduce over h (8 groups of 8 lanes)
        f0 += SWZ8(f0);  f1 += SWZ8(f1);  f2 += SWZ8(f2);  f3 += SWZ8(f3);
        f0 += SWZ16(f0); f1 += SWZ16(f1); f2 += SWZ16(f2); f3 += SWZ16(f3);
        f0 += SX32(f0);  f1 += SX32(f1);  f2 += SX32(f2);  f3 += SX32(f3);

        if (h == 0)
            *(float4*)(acc + (size_t)n * 32 + k * 4) = float4{f0, f1, f2, f3};
    }
}

// ============================================================================
// K3: out[n][m][c] = sum_k acc[n][k][m] * w_out[k][c]. lane -> c = {2L, 2L+1}
// ============================================================================
__global__ __launch_bounds__(256, 4) void k3_wout(
    const float* __restrict__ acc,    // (N,32)
    const float* __restrict__ w_out,  // (8,128)
    float* __restrict__ out, int N, int nwaves)
{
    const int lane = threadIdx.x & 63;
    const int wave = blockIdx.x * (blockDim.x >> 6) + (threadIdx.x >> 6);
    float wc0[8], wc1[8];
    #pragma unroll
    for (int kk = 0; kk < 8; kk++) {
        wc0[kk] = w_out[kk * 128 + lane * 2];
        wc1[kk] = w_out[kk * 128 + lane * 2 + 1];
    }
    for (int n = wave; n < N; n += nwaves) {
        int nu = __builtin_amdgcn_readfirstlane(n);
        const float* a = acc + (size_t)nu * 32;
        float o0[4] = {0.f, 0.f, 0.f, 0.f}, o1[4] = {0.f, 0.f, 0.f, 0.f};
        #pragma unroll
        for (int kk = 0; kk < 8; kk++) {
            #pragma unroll
            for (int m = 0; m < 4; m++) {
                float av = a[kk * 4 + m];
                o0[m] += av * wc0[kk];
                o1[m] += av * wc1[kk];
            }
        }
        float* op = out + (size_t)nu * 512;
        #pragma unroll
        for (int m = 0; m < 4; m++)
            *(float2*)(op + m * 128 + lane * 2) = float2{o0[m], o1[m]};
    }
}

extern "C" void kernel_launch(void* const* d_in, const int* in_sizes, int n_in,
                              void* d_out, int out_size, void* d_ws, size_t ws_size,
                              hipStream_t stream) {
    const float* s_feats  = (const float*)d_in[0];
    const float* s_points = (const float*)d_in[1];
    const int*   nbr      = (const int*)d_in[2];
    const float* ln_w     = (const float*)d_in[3];
    const float* ln_b     = (const float*)d_in[4];
    const float* w_in     = (const float*)d_in[5];
    const float* w_out    = (const float*)d_in[6];
    const float* so2_w0   = (const float*)d_in[7];
    const float* so2_wr   = (const float*)d_in[8];
    const float* so2_wi   = (const float*)d_in[9];
    float* out = (float*)d_out;

    int N = in_sizes[0] / 512;
    float* ys  = (float*)d_ws;            // N*64 floats
    float* acc = ys + (size_t)N * 64;     // N*32 floats

    const int NB = 1250;                  // 256 thr = 4 waves/block
    const int nwaves = NB * 4;
    k1_ln_proj<<<NB, 256, 0, stream>>>(s_feats, ln_w, ln_b, w_in, ys, N, nwaves);
    k2_edges<<<NB, 256, 0, stream>>>(ys, s_points, nbr, so2_w0, so2_wr, so2_wi, acc, N, nwaves);
    k3_wout<<<NB, 256, 0, stream>>>(acc, w_out, out, N, nwaves);
}

// Round 3
// 54.712 us; speedup vs baseline: 3.6044x; 1.8189x over previous
//
#include <hip/hip_runtime.h>
#include <math.h>

// ---- cross-lane helpers (LDS-pipe ds_swizzle, single instruction) ----
#define SWZ8(x)  __int_as_float(__builtin_amdgcn_ds_swizzle(__float_as_int(x), 0x201F)) // lane^8
#define SWZ16(x) __int_as_float(__builtin_amdgcn_ds_swizzle(__float_as_int(x), 0x401F)) // lane^16
#define SX32(x)  __shfl_xor((x), 32)

// ============================================================================
// K1: fused LayerNorm + both input projections. ONE node per wave (pure TLP).
//   ys[n][k*4+m]      = LN(x_n)[m] . w_in[0:128, k]
//   ys[n][32+k*4+m]   = LN(x_n)[m] . w_in[128:256, k]
// lane = (cg = lane>>3 owns 16 channels, kq = lane&7 owns output k)
// ============================================================================
__global__ __launch_bounds__(256, 4) void k1_ln_proj(
    const float* __restrict__ s_feats,
    const float* __restrict__ ln_w,   // (2,128)
    const float* __restrict__ ln_b,   // (128)
    const float* __restrict__ w_in,   // (256,8)
    float* __restrict__ ys,           // (N,64)
    int N)
{
    const int lane = threadIdx.x & 63;
    const int kq = lane & 7;
    const int cg = lane >> 3;
    const int n = blockIdx.x * 4 + (threadIdx.x >> 6);

    // per-lane constant weights: w_in premultiplied by ln scale rows
    float wa0[16], wa1[16], wb0[16], wb1[16];
    float B1 = 0.f, C1 = 0.f, B2 = 0.f, C2 = 0.f;
    #pragma unroll
    for (int t = 0; t < 16; t++) {
        int c = cg * 16 + t;
        float w1 = w_in[c * 8 + kq];
        float w2 = w_in[(128 + c) * 8 + kq];
        float l0 = ln_w[c], l1 = ln_w[128 + c], lb = ln_b[c];
        wa0[t] = w1 * l0; wa1[t] = w1 * l1;
        wb0[t] = w2 * l0; wb1[t] = w2 * l1;
        B1 += w1 * l0; C1 += lb * w1;
        B2 += w2 * l0; C2 += lb * w2;
    }
    B1 += SWZ8(B1);  C1 += SWZ8(C1);  B2 += SWZ8(B2);  C2 += SWZ8(C2);
    B1 += SWZ16(B1); C1 += SWZ16(C1); B2 += SWZ16(B2); C2 += SWZ16(C2);
    B1 += SX32(B1);  C1 += SX32(C1);  B2 += SX32(B2);  C2 += SX32(C2);

    if (n >= N) return;

    const float* sp = s_feats + (size_t)n * 512 + cg * 16;
    float accY[4] = {0.f, 0.f, 0.f, 0.f};
    float accS[4] = {0.f, 0.f, 0.f, 0.f};
    float ssum = 0.f, sq0 = 0.f, sq1 = 0.f;
    #pragma unroll
    for (int m = 0; m < 4; m++) {
        #pragma unroll
        for (int i = 0; i < 4; i++) {
            float4 v = *(const float4*)(sp + m * 128 + i * 4);
            float e0 = v.x, e1 = v.y, e2 = v.z, e3 = v.w;
            if (m == 0) {
                accY[0] += e0 * wa0[i*4+0] + e1 * wa0[i*4+1] + e2 * wa0[i*4+2] + e3 * wa0[i*4+3];
                accS[0] += e0 * wb0[i*4+0] + e1 * wb0[i*4+1] + e2 * wb0[i*4+2] + e3 * wb0[i*4+3];
                ssum += e0 + e1 + e2 + e3;
                sq0  += e0 * e0 + e1 * e1 + e2 * e2 + e3 * e3;
            } else {
                accY[m] += e0 * wa1[i*4+0] + e1 * wa1[i*4+1] + e2 * wa1[i*4+2] + e3 * wa1[i*4+3];
                accS[m] += e0 * wb1[i*4+0] + e1 * wb1[i*4+1] + e2 * wb1[i*4+2] + e3 * wb1[i*4+3];
                sq1  += e0 * e0 + e1 * e1 + e2 * e2 + e3 * e3;
            }
        }
    }
    #define RED_ALL(FN) \
        accY[0] += FN(accY[0]); accY[1] += FN(accY[1]); accY[2] += FN(accY[2]); accY[3] += FN(accY[3]); \
        accS[0] += FN(accS[0]); accS[1] += FN(accS[1]); accS[2] += FN(accS[2]); accS[3] += FN(accS[3]); \
        ssum += FN(ssum); sq0 += FN(sq0); sq1 += FN(sq1);
    RED_ALL(SWZ8)
    RED_ALL(SWZ16)
    RED_ALL(SX32)
    #undef RED_ALL

    float mean = ssum * (1.0f / 128.0f);
    float r0 = rsqrtf((sq0 - ssum * mean) * (1.0f / 128.0f) + 1e-5f);
    float r1 = rsqrtf(sq1 * (1.0f / 128.0f) + 1e-5f);

    float aA = (cg & 2) ? ((cg & 1) ? accY[3] : accY[2]) : ((cg & 1) ? accY[1] : accY[0]);
    float aB = (cg & 2) ? ((cg & 1) ? accS[3] : accS[2]) : ((cg & 1) ? accS[1] : accS[0]);
    float av = (cg & 4) ? aB : aA;
    float Bv = (cg & 4) ? B2 : B1;
    float Cv = (cg & 4) ? C2 : C1;
    bool isM0 = (cg & 3) == 0;
    float outv = isM0 ? (r0 * (av - mean * Bv) + Cv) : (r1 * av);
    ys[(size_t)n * 64 + kq * 4 + (cg & 3) + ((cg & 4) << 3)] = outv;
}

// ============================================================================
// K2: per-edge tensor product + fused w_out epilogue. ONE node per wave.
// lane = (h = lane>>3, k = lane&7). Wave-local LDS transposes (no barriers).
// ============================================================================
#define TROW 36   // padded stride (floats) for the [h][j][4] transpose buffer

__global__ __launch_bounds__(256, 4) void k2_edges(
    const float* __restrict__ ys,       // (N,64)
    const float* __restrict__ s_points, // (N,3)
    const int*   __restrict__ nbr,      // (N,9)
    const float* __restrict__ w0,       // (16,16)
    const float* __restrict__ wr,       // (8,8)
    const float* __restrict__ wi,       // (8,8)
    const float* __restrict__ w_out,    // (8,128)
    float* __restrict__ out,            // (N,4,128)
    int N)
{
    __shared__ float tbuf[4][8 * TROW]; // per-wave transpose scratch
    __shared__ float abuf[4][32];       // per-wave acc[k][m]

    const int lane = threadIdx.x & 63;
    const int h = lane >> 3, k = lane & 7;
    const int wv = threadIdx.x >> 6;
    const int n = blockIdx.x * 4 + wv;

    // per-lane constant mixing weights
    float c00[8], c08[8], c10[8], c18[8], cwr[8], cwi[8];
    #pragma unroll
    for (int j = 0; j < 8; j++) {
        c00[j] = w0[j * 16 + k];
        c08[j] = w0[(8 + j) * 16 + k];
        c10[j] = w0[j * 16 + 8 + k];
        c18[j] = w0[(8 + j) * 16 + 8 + k];
        cwr[j] = wr[j * 8 + k];
        cwi[j] = wi[j * 8 + k];
    }
    // epilogue weights: lane -> channels {2*lane, 2*lane+1}
    float wc0[8], wc1[8];
    #pragma unroll
    for (int kk = 0; kk < 8; kk++) {
        float2 w2v = *(const float2*)&w_out[kk * 128 + lane * 2];
        wc0[kk] = w2v.x; wc1[kk] = w2v.y;
    }

    if (n >= N) return;

    int idx = nbr[n * 9 + 1 + h];
    bool mk = idx < N;
    float px = s_points[n * 3], py = s_points[n * 3 + 1], pz = s_points[n * 3 + 2];
    float nx = mk ? s_points[idx * 3]     : 0.f;
    float ny = mk ? s_points[idx * 3 + 1] : 0.f;
    float nz = mk ? s_points[idx * 3 + 2] : 0.f;
    float vx = nx - px, vy = ny - py, vz = nz - pz;
    float nn = sqrtf(vx * vx + vy * vy + vz * vz);
    float inv = 1.0f / (nn + 1e-9f);
    float ux = vx * inv, uy = vy * inv, uz = vz * inv;
    float cz = uz;
    float kx = uy, ky = -ux;
    bool safe = cz > -0.999f;
    float id = safe ? 1.0f / (1.0f + cz) : 1.0f;
    float D1[3][3];
    {
        float R00, R01, R02, R10, R11, R12, R20, R21, R22;
        if (safe) {
            R00 = 1.0f - ky * ky * id; R01 = kx * ky * id;        R02 = ky;
            R10 = kx * ky * id;        R11 = 1.0f - kx * kx * id; R12 = -kx;
            R20 = -ky;                 R21 = kx;                  R22 = 1.0f - (kx * kx + ky * ky) * id;
        } else {
            R00 = 1.0f; R01 = 0.0f; R02 = 0.0f;
            R10 = 0.0f; R11 = -1.0f; R12 = 0.0f;
            R20 = 0.0f; R21 = 0.0f; R22 = -1.0f;
        }
        D1[0][0] = R11; D1[0][1] = R12; D1[0][2] = R10;
        D1[1][0] = R21; D1[1][1] = R22; D1[1][2] = R20;
        D1[2][0] = R01; D1[2][1] = R02; D1[2][2] = R00;
    }

    float4 yv = mk ? *(const float4*)(ys + (size_t)idx * 64 + k * 4)
                   : float4{0.f, 0.f, 0.f, 0.f};
    float4 sv = *(const float4*)(ys + (size_t)n * 64 + 32 + k * 4);
    float msg0 = yv.x + sv.x;
    float msg1 = yv.y + sv.y;
    float msg2 = yv.z + sv.z;
    float msg3 = yv.w + sv.w;

    float l1_0 = D1[0][0] * msg1 + D1[0][1] * msg2 + D1[0][2] * msg3;
    float l1_1 = D1[1][0] * msg1 + D1[1][1] * msg2 + D1[1][2] * msg3;
    float l1_2 = D1[2][0] * msg1 + D1[2][1] * msg2 + D1[2][2] * msg3;

    // ---- wave-local transpose: [h][k] -> read by j (conflict-free, stride 36) ----
    *(float4*)&tbuf[wv][h * TROW + k * 4] = float4{msg0, l1_0, l1_1, l1_2};

    float m00 = 0.f, m01 = 0.f, ypl = 0.f, yml = 0.f;
    #pragma unroll
    for (int j = 0; j < 8; j++) {
        float4 t = *(const float4*)&tbuf[wv][h * TROW + j * 4];
        m00 += t.x * c00[j] + t.z * c08[j];
        m01 += t.x * c10[j] + t.z * c18[j];
        ypl += t.w * cwr[j] - t.y * cwi[j];
        yml += t.y * cwr[j] + t.w * cwi[j];
    }

    float f0 = m00;
    float f1 = D1[0][0] * yml + D1[1][0] * m01 + D1[2][0] * ypl;
    float f2 = D1[0][1] * yml + D1[1][1] * m01 + D1[2][1] * ypl;
    float f3 = D1[0][2] * yml + D1[1][2] * m01 + D1[2][2] * ypl;

    // ---- reduce over h (xor butterfly -> every lane holds full sum for its k) ----
    f0 += SWZ8(f0);  f1 += SWZ8(f1);  f2 += SWZ8(f2);  f3 += SWZ8(f3);
    f0 += SWZ16(f0); f1 += SWZ16(f1); f2 += SWZ16(f2); f3 += SWZ16(f3);
    f0 += SX32(f0);  f1 += SX32(f1);  f2 += SX32(f2);  f3 += SX32(f3);

    // ---- fused epilogue: acc[k][m] to LDS (8 lanes), broadcast-read all 32 ----
    if (lane < 8)
        *(float4*)&abuf[wv][lane * 4] = float4{f0, f1, f2, f3};

    float o0[4] = {0.f, 0.f, 0.f, 0.f}, o1[4] = {0.f, 0.f, 0.f, 0.f};
    #pragma unroll
    for (int kk = 0; kk < 8; kk++) {
        float4 a = *(const float4*)&abuf[wv][kk * 4];   // broadcast read
        o0[0] += a.x * wc0[kk]; o1[0] += a.x * wc1[kk];
        o0[1] += a.y * wc0[kk]; o1[1] += a.y * wc1[kk];
        o0[2] += a.z * wc0[kk]; o1[2] += a.z * wc1[kk];
        o0[3] += a.w * wc0[kk]; o1[3] += a.w * wc1[kk];
    }
    float* op = out + (size_t)n * 512;
    #pragma unroll
    for (int m = 0; m < 4; m++)
        *(float2*)(op + m * 128 + lane * 2) = float2{o0[m], o1[m]};
}

extern "C" void kernel_launch(void* const* d_in, const int* in_sizes, int n_in,
                              void* d_out, int out_size, void* d_ws, size_t ws_size,
                              hipStream_t stream) {
    const float* s_feats  = (const float*)d_in[0];
    const float* s_points = (const float*)d_in[1];
    const int*   nbr      = (const int*)d_in[2];
    const float* ln_w     = (const float*)d_in[3];
    const float* ln_b     = (const float*)d_in[4];
    const float* w_in     = (const float*)d_in[5];
    const float* w_out    = (const float*)d_in[6];
    const float* so2_w0   = (const float*)d_in[7];
    const float* so2_wr   = (const float*)d_in[8];
    const float* so2_wi   = (const float*)d_in[9];
    float* out = (float*)d_out;

    int N = in_sizes[0] / 512;
    float* ys = (float*)d_ws;   // N*64 floats

    int nb = (N + 3) / 4;       // one node per wave, 4 waves per block
    k1_ln_proj<<<nb, 256, 0, stream>>>(s_feats, ln_w, ln_b, w_in, ys, N);
    k2_edges<<<nb, 256, 0, stream>>>(ys, s_points, nbr, so2_w0, so2_wr, so2_wi,
                                     w_out, out, N);
}